// Round 6
// baseline (527.900 us; speedup 1.0000x reference)
//
#include <hip/hip_runtime.h>

// VectorQuantizer on MI355X — round 6: MFMA bf16 shortlist + exact rescore.
// Scoring arithmetic for the FINAL argmin is bit-identical to rounds 3/5
// (fp32 fmaf chain over ascending 32-d chunks -> fp64 chunk fold ->
//  d32 = fl32(fl32(T+U) - 2*fl32(dot)), first-index tie-break), applied only
// to a provably-sufficient candidate set selected by a bf16 MFMA pass.
// x: (32,256,32,32) fp32, codebook: (1024,256) fp32.
// Outputs concat: quantized (8388608 f32), vq_loss (1 f32), indices (32768 as f32).

#define NUM_K 1024
#define DIM   256
#define HW    1024
#define N_TOT 32768
#define LOSS_OFF 8388608
#define IDX_OFF  8388609
#define CAP   64
#define WIN   2.0e-3f
// scratch regions inside out[] (floats); quantized write happens last
#define CAND_OFF 4194304   // int[32768][64] = 2M ints (after zb's 4M floats)

typedef __attribute__((ext_vector_type(8))) short bf16x8;
typedef __attribute__((ext_vector_type(4))) float f32x4;

__device__ __forceinline__ ushort f2bf(float f) {   // RNE f32 -> bf16 bits
    unsigned u = __float_as_uint(f);
    unsigned r = (u + 0x7fffu + ((u >> 16) & 1u)) >> 16;
    return (ushort)r;
}

// numpy pairwise sum of squares over 256 elements, exact numpy order (as r3-r5)
__device__ __forceinline__ float np_sumsq_256(const float* p, int stride) {
    float s[2];
    #pragma unroll
    for (int h = 0; h < 2; ++h) {
        const float* base = p + (size_t)h * 128 * stride;
        float r[8];
        #pragma unroll
        for (int j = 0; j < 8; ++j) {
            float v = base[(size_t)j * stride];
            r[j] = __fmul_rn(v, v);
        }
        for (int i = 8; i < 128; i += 8) {
            #pragma unroll
            for (int j = 0; j < 8; ++j) {
                float v = base[(size_t)(i + j) * stride];
                r[j] = __fadd_rn(r[j], __fmul_rn(v, v));
            }
        }
        s[h] = __fadd_rn(__fadd_rn(__fadd_rn(r[0], r[1]), __fadd_rn(r[2], r[3])),
                         __fadd_rn(__fadd_rn(r[4], r[5]), __fadd_rn(r[6], r[7])));
    }
    return __fadd_rn(s[0], s[1]);
}

// exact per-(row,code) scoring chain — BIT-IDENTICAL to rounds 3/5
__device__ __forceinline__ float exact_d32(const float* zsrow, const float* crow,
                                           float Tn, float Uk) {
    double accd = 0.0;
    for (int dc = 0; dc < 8; ++dc) {
        float af = 0.f;
        const float* zp = zsrow + dc * 32;
        const float* cp = crow + dc * 32;
        #pragma unroll
        for (int q = 0; q < 8; ++q) {
            float4 zv = *(const float4*)(zp + q * 4);
            float4 cv = *(const float4*)(cp + q * 4);
            af = fmaf(zv.x, cv.x, af);
            af = fmaf(zv.y, cv.y, af);
            af = fmaf(zv.z, cv.z, af);
            af = fmaf(zv.w, cv.w, af);
        }
        accd += (double)af;
    }
    float m32 = (float)accd;
    float cc  = __fmul_rn(2.0f, m32);
    float t1  = __fadd_rn(Tn, Uk);
    return __fsub_rn(t1, cc);
}

// blocks 0..511: x tile -> zb bf16 + t2 norms; blocks 512..515: cb -> eb bf16 + u2
__global__ __launch_bounds__(256) void prep(const float* __restrict__ x,
                                            const float* __restrict__ cb,
                                            float* __restrict__ u2,
                                            float* __restrict__ t2,
                                            ushort* __restrict__ eb,
                                            ushort* __restrict__ zb,
                                            float* __restrict__ out) {
    const int bid = blockIdx.x;
    const int t   = threadIdx.x;
    if (bid >= 512) {
        int k = (bid - 512) * 256 + t;
        const float* src = cb + (size_t)k * DIM;
        u2[k] = np_sumsq_256(src, 1);
        ushort* dst = eb + (size_t)k * DIM;
        alignas(16) ushort hs[8];
        for (int d = 0; d < DIM; d += 8) {
            #pragma unroll
            for (int j = 0; j < 8; ++j) hs[j] = f2bf(src[d + j]);
            *(uint4*)(dst + d) = *(const uint4*)hs;
        }
        return;
    }
    __shared__ float zT[DIM][68];       // pad 64->68 to break bank strides
    if (bid == 0 && t == 0) out[LOSS_OFF] = 0.f;
    const int n0 = bid * 64;
    const int b  = n0 >> 10;
    const int r0 = n0 & (HW - 1);
    const size_t xbase = (size_t)b * (DIM * HW) + r0;
    {
        const int f4 = (t & 15) * 4;
        const int dr = t >> 4;
        #pragma unroll
        for (int it = 0; it < 16; ++it) {
            int d = it * 16 + dr;
            float4 v = *(const float4*)(x + xbase + (size_t)d * HW + f4);
            *(float4*)&zT[d][f4] = v;
        }
    }
    __syncthreads();
    if (t < 64) t2[n0 + t] = np_sumsq_256(&zT[0][t], 68);
    // pack zb[n][d] bf16: thread -> row r = t>>2, d-segment (t&3)*64
    const int r   = t >> 2;
    const int ds0 = (t & 3) * 64;
    ushort* dst = zb + (size_t)(n0 + r) * DIM + ds0;
    alignas(16) ushort hs[8];
    for (int i = 0; i < 64; i += 8) {
        #pragma unroll
        for (int j = 0; j < 8; ++j) hs[j] = f2bf(zT[ds0 + i + j][r]);
        *(uint4*)(dst + i) = *(const uint4*)hs;
    }
}

// MFMA gemm + per-64k-tile candidate emission. Block: 64 m x 64 k, wave w owns
// rows m0+16w..+15. Layouts (verified m89/m91): A[m=lane&15][k=quad*8+j],
// B[n=lane&15][k=quad*8+j], D: row=quad*4+reg, col=lane&15.
__global__ __launch_bounds__(256) void gemm_emit(const ushort* __restrict__ zb,
                                                 const ushort* __restrict__ eb,
                                                 const float* __restrict__ u2,
                                                 const float* __restrict__ t2,
                                                 int* __restrict__ cnt,
                                                 int* __restrict__ cand) {
    const int t    = threadIdx.x;
    const int w    = t >> 6;
    const int lane = t & 63;
    const int col  = lane & 15;
    const int quad = lane >> 4;
    const int kg = blockIdx.x & 15;     // 16 k-groups of 64
    const int mg = blockIdx.x >> 4;     // 512 m-groups of 64
    const int m0 = mg * 64 + w * 16;
    const int k0 = kg * 64;

    const ushort* A  = zb + (size_t)(m0 + col) * DIM + quad * 8;
    const ushort* B0 = eb + (size_t)(k0 + col) * DIM + quad * 8;

    f32x4 acc0 = {0.f, 0.f, 0.f, 0.f};
    f32x4 acc1 = acc0, acc2 = acc0, acc3 = acc0;
    #pragma unroll
    for (int dc = 0; dc < 8; ++dc) {
        bf16x8 a  = *(const bf16x8*)(A  + dc * 32);
        bf16x8 b0 = *(const bf16x8*)(B0 + dc * 32);
        bf16x8 b1 = *(const bf16x8*)(B0 + 16 * DIM + dc * 32);
        bf16x8 b2 = *(const bf16x8*)(B0 + 32 * DIM + dc * 32);
        bf16x8 b3 = *(const bf16x8*)(B0 + 48 * DIM + dc * 32);
        acc0 = __builtin_amdgcn_mfma_f32_16x16x32_bf16(a, b0, acc0, 0, 0, 0);
        acc1 = __builtin_amdgcn_mfma_f32_16x16x32_bf16(a, b1, acc1, 0, 0, 0);
        acc2 = __builtin_amdgcn_mfma_f32_16x16x32_bf16(a, b2, acc2, 0, 0, 0);
        acc3 = __builtin_amdgcn_mfma_f32_16x16x32_bf16(a, b3, acc3, 0, 0, 0);
    }

    // approx distances + per-row (64k-tile) min
    float4 tv = *(const float4*)(t2 + m0 + quad * 4);    // rows quad*4 + r
    float ta[4] = {tv.x, tv.y, tv.z, tv.w};
    float da[4][4];                                      // [j][r]
    float rmin[4] = {3.4e38f, 3.4e38f, 3.4e38f, 3.4e38f};
    #pragma unroll
    for (int j = 0; j < 4; ++j) {
        float uk = u2[k0 + j * 16 + col];
        f32x4 acc = (j == 0) ? acc0 : (j == 1) ? acc1 : (j == 2) ? acc2 : acc3;
        #pragma unroll
        for (int r = 0; r < 4; ++r) {
            float d = (ta[r] + uk) - 2.0f * acc[r];
            da[j][r] = d;
            rmin[r] = fminf(rmin[r], d);
        }
    }
    #pragma unroll
    for (int off = 1; off < 16; off <<= 1) {
        #pragma unroll
        for (int r = 0; r < 4; ++r)
            rmin[r] = fminf(rmin[r], __shfl_xor(rmin[r], off, 64));
    }
    // emit candidates within WIN of the tile row-min
    #pragma unroll
    for (int j = 0; j < 4; ++j) {
        #pragma unroll
        for (int r = 0; r < 4; ++r) {
            if (da[j][r] <= rmin[r] + WIN) {
                int m = m0 + quad * 4 + r;
                int pos = atomicAdd(&cnt[m], 1);
                if (pos < CAP) cand[(size_t)m * CAP + pos] = k0 + j * 16 + col;
            }
        }
    }
}

// one wave per row: exact rescore of candidates, lexicographic (d32,k) argmin
__global__ __launch_bounds__(256) void rescore(const float* __restrict__ x,
                                               const float* __restrict__ cb,
                                               const float* __restrict__ u2,
                                               const float* __restrict__ t2,
                                               const int* __restrict__ cnt,
                                               const int* __restrict__ cand,
                                               int* __restrict__ bidx,
                                               float* __restrict__ out) {
    __shared__ float zs[4][DIM];
    const int t    = threadIdx.x;
    const int w    = t >> 6;
    const int lane = t & 63;
    const int n    = blockIdx.x * 4 + w;
    const int b    = n >> 10;
    const int r    = n & (HW - 1);
    const float* xb = x + (size_t)b * (DIM * HW) + r;
    #pragma unroll
    for (int i = 0; i < 4; ++i)
        zs[w][lane * 4 + i] = xb[(size_t)(lane * 4 + i) * HW];
    __syncthreads();

    const float Tn = t2[n];
    const int c = cnt[n];
    float bv; int bk;
    if (c <= CAP) {
        int kc = (lane < c) ? cand[(size_t)n * CAP + lane] : -1;
        if (kc >= 0) {
            bv = exact_d32(zs[w], cb + (size_t)kc * DIM, Tn, u2[kc]);
            bk = kc;
        } else {
            bv = 3.4e38f; bk = 0x7fffffff;
        }
    } else {
        // overflow fallback: exact full scan (wave-uniform branch)
        bv = 3.4e38f; bk = 0x7fffffff;
        for (int it = 0; it < NUM_K / 64; ++it) {
            int kc = it * 64 + lane;
            float d = exact_d32(zs[w], cb + (size_t)kc * DIM, Tn, u2[kc]);
            if (d < bv || (d == bv && kc < bk)) { bv = d; bk = kc; }
        }
    }
    #pragma unroll
    for (int off = 1; off < 64; off <<= 1) {
        float ov = __shfl_xor(bv, off, 64);
        int   ok = __shfl_xor(bk, off, 64);
        if (ov < bv || (ov == bv && ok < bk)) { bv = ov; bk = ok; }
    }
    if (lane == 0) {
        bidx[n] = bk;
        out[IDX_OFF + n] = (float)bk;
    }
}

// gather quantized + fused loss (same as round 5, bestk from bidx)
__global__ __launch_bounds__(256) void epilogue(const float* __restrict__ x,
                                                const float* __restrict__ cb,
                                                const int* __restrict__ bidx,
                                                float* __restrict__ out) {
    __shared__ float wsum[4];
    const int t  = threadIdx.x;
    const int n0 = blockIdx.x * 64;
    const int b  = n0 >> 10;
    const int r0 = n0 & (HW - 1);
    const size_t xbase = (size_t)b * (DIM * HW) + r0;
    float lsum = 0.f;
    const int m  = t & 63;
    const int kq = bidx[n0 + m];
    const float* crow = cb + (size_t)kq * DIM;
    for (int c = (t >> 6); c < DIM; c += 4) {
        float qv = crow[c];
        float xv = x[xbase + (size_t)c * HW + m];
        float d  = qv - xv;
        lsum = fmaf(d, d, lsum);
        out[xbase + (size_t)c * HW + m] = qv;
    }
    #pragma unroll
    for (int off = 32; off > 0; off >>= 1) lsum += __shfl_down(lsum, off, 64);
    if ((t & 63) == 0) wsum[t >> 6] = lsum;
    __syncthreads();
    if (t == 0) {
        float s = (wsum[0] + wsum[1]) + (wsum[2] + wsum[3]);
        atomicAdd(out + LOSS_OFF, s * (1.25f / 8388608.0f));
    }
}

extern "C" void kernel_launch(void* const* d_in, const int* in_sizes, int n_in,
                              void* d_out, int out_size, void* d_ws, size_t ws_size,
                              hipStream_t stream) {
    const float* x  = (const float*)d_in[0];
    const float* cb = (const float*)d_in[1];
    float* out = (float*)d_out;

    // workspace layout (<1 MB)
    float*  u2   = (float*)d_ws;                 // 4 KB
    float*  t2   = u2 + NUM_K;                   // 128 KB
    ushort* eb   = (ushort*)(t2 + N_TOT);        // 512 KB bf16 codebook
    int*    cnt  = (int*)(eb + (size_t)NUM_K * DIM);   // 128 KB
    int*    bidx = cnt + N_TOT;                  // 128 KB

    // big scratch lives in out[] (overwritten by epilogue at the end)
    ushort* zb   = (ushort*)out;                 // 16 MB bf16 x, [n][d]
    int*    cand = (int*)(out + CAND_OFF);       // 8 MB candidate lists

    hipMemsetAsync(cnt, 0, N_TOT * sizeof(int), stream);
    prep<<<516, 256, 0, stream>>>(x, cb, u2, t2, eb, zb, out);
    gemm_emit<<<8192, 256, 0, stream>>>(zb, eb, u2, t2, cnt, cand);
    rescore<<<8192, 256, 0, stream>>>(x, cb, u2, t2, cnt, cand, bidx, out);
    epilogue<<<512, 256, 0, stream>>>(x, cb, bidx, out);
}